// Round 2
// baseline (305.054 us; speedup 1.0000x reference)
//
#include <hip/hip_runtime.h>
#include <stdint.h>

#define T_STEPS 100
#define BB 4
#define NN 512
#define KK 10

// ---------------- threefry2x32 (JAX-compatible, 20 rounds) ----------------
__device__ __forceinline__ uint32_t rotl32(uint32_t v, int d) {
  return (v << d) | (v >> (32 - d));
}

__device__ __forceinline__ void tf2x32(uint32_t k0, uint32_t k1,
                                       uint32_t& x0, uint32_t& x1) {
  uint32_t k2 = k0 ^ k1 ^ 0x1BD11BDAu;
  x0 += k0; x1 += k1;
#define TFR(r) { x0 += x1; x1 = rotl32(x1, r); x1 ^= x0; }
  TFR(13) TFR(15) TFR(26) TFR(6)   x0 += k1; x1 += k2 + 1u;
  TFR(17) TFR(29) TFR(16) TFR(24)  x0 += k2; x1 += k0 + 2u;
  TFR(13) TFR(15) TFR(26) TFR(6)   x0 += k0; x1 += k1 + 3u;
  TFR(17) TFR(29) TFR(16) TFR(24)  x0 += k1; x1 += k2 + 4u;
  TFR(13) TFR(15) TFR(26) TFR(6)   x0 += k2; x1 += k0 + 5u;
#undef TFR
}

__device__ __forceinline__ float bits_to_u01(uint32_t bits) {
  return __fsub_rn(__uint_as_float((bits >> 9) | 0x3f800000u), 1.0f);
}

// XLA ErfInv32 (Giles), w = -log((1-x)(1+x)) exactly as ElementalIrEmitter
__device__ __forceinline__ float erfinv_f32(float x) {
  float w = -logf(__fmul_rn(__fsub_rn(1.0f, x), __fadd_rn(1.0f, x)));
  float p;
  if (w < 5.0f) {
    w = __fsub_rn(w, 2.5f);
    p = 2.81022636e-08f;
    p = __fadd_rn(__fmul_rn(p, w), 3.43273939e-07f);
    p = __fadd_rn(__fmul_rn(p, w), -3.5233877e-06f);
    p = __fadd_rn(__fmul_rn(p, w), -4.39150654e-06f);
    p = __fadd_rn(__fmul_rn(p, w), 0.00021858087f);
    p = __fadd_rn(__fmul_rn(p, w), -0.00125372503f);
    p = __fadd_rn(__fmul_rn(p, w), -0.00417768164f);
    p = __fadd_rn(__fmul_rn(p, w), 0.246640727f);
    p = __fadd_rn(__fmul_rn(p, w), 1.50140941f);
  } else {
    w = __fsub_rn(sqrtf(w), 3.0f);
    p = -0.000200214257f;
    p = __fadd_rn(__fmul_rn(p, w), 0.000100950558f);
    p = __fadd_rn(__fmul_rn(p, w), 0.00134934322f);
    p = __fadd_rn(__fmul_rn(p, w), -0.00367342844f);
    p = __fadd_rn(__fmul_rn(p, w), 0.00573950773f);
    p = __fadd_rn(__fmul_rn(p, w), -0.0076224613f);
    p = __fadd_rn(__fmul_rn(p, w), 0.00943887047f);
    p = __fadd_rn(__fmul_rn(p, w), 1.00167406f);
    p = __fadd_rn(__fmul_rn(p, w), 2.83297682f);
  }
  return __fmul_rn(p, x);
}

// ---------------- Kernel A: softmax-mixture mean/std + L = log(ep)-log(1-ep) --
__global__ void prep_kernel(const float* __restrict__ mu,
                            const float* __restrict__ sig,
                            const float* __restrict__ pi,
                            float* __restrict__ sm, float* __restrict__ ss,
                            double* __restrict__ Ld) {
  int m = blockIdx.x * blockDim.x + threadIdx.x;
  if (m >= BB * NN) return;
  const float* pp = pi + m * KK;
  float mx = pp[0];
  for (int k = 1; k < KK; k++) mx = fmaxf(mx, pp[k]);
  float e[KK]; float s = 0.0f;
  for (int k = 0; k < KK; k++) { e[k] = expf(__fsub_rn(pp[k], mx)); s = __fadd_rn(s, e[k]); }
  float smv = 0.0f, ssv = 0.0f, eps = 0.0f;
  for (int k = 0; k < KK; k++) {
    float p = e[k] / s;
    smv = __fadd_rn(smv, __fmul_rn(p, mu[m * KK + k]));
    ssv = __fadd_rn(ssv, __fmul_rn(p, sig[m * KK + k]));
    eps = __fadd_rn(eps, pp[k]);
  }
  sm[m] = smv; ss[m] = ssv;
  float ep = fminf(fmaxf(eps, 1e-8f), 1.0f);
  float lep = logf(ep);
  float l1 = logf(__fsub_rn(1.0f, ep));
  Ld[m] = (double)lep - (double)l1;
}

// -------- Kernel B: JAX partitionable-threefry RNG -> pm table + uniforms ----
__global__ void rng_kernel(const float* __restrict__ sm,
                           const float* __restrict__ ss,
                           float* __restrict__ pm, float* __restrict__ uacc) {
  int id = blockIdx.x * blockDim.x + threadIdx.x;
  if (id >= T_STEPS * BB * NN) return;
  int t = id >> 11;        // /2048
  int m = id & 2047;       // b*512+n

  // kk = fold_in(key(42), t) = threefry([0,42], [0,t])  (fold_in is mode-invariant)
  uint32_t kk0 = 0u, kk1 = (uint32_t)t;
  tf2x32(0u, 42u, kk0, kk1);
  // partitionable split (foldlike): k_noise = enc_kk(0,0), k_unif = enc_kk(0,1)
  uint32_t n0 = 0u, n1 = 0u; tf2x32(kk0, kk1, n0, n1);
  // partitionable random_bits(32): bits[m] = x0^x1 of enc_key(hi=0, lo=m)
  uint32_t y0 = 0u, y1 = (uint32_t)m;
  tf2x32(n0, n1, y0, y1);
  uint32_t bits = y0 ^ y1;

  float u01 = bits_to_u01(bits);
  const float lo = -0.99999994f;  // nextafter(-1,0) f32; span (1-lo) rounds to 2.0f
  float u = fmaxf(lo, __fadd_rn(__fmul_rn(u01, 2.0f), lo));
  float z = __fmul_rn(1.41421356237309515f, erfinv_f32(u));
  pm[id] = __fadd_rn(sm[m], __fmul_rn(z, ss[m]));

  if (m < 4) {
    uint32_t u0 = 0u, u1 = 1u; tf2x32(kk0, kk1, u0, u1);     // k_unif
    uint32_t c0 = 0u, c1 = (uint32_t)m;
    tf2x32(u0, u1, c0, c1);
    uacc[t * 4 + m] = bits_to_u01(c0 ^ c1);
  }
}

// ---------------- Kernel C: llt[t][b][j] = sum_i sigmoid(pm_i*pm_j)*L[b,i] ---
__global__ __launch_bounds__(512) void ll_kernel(const float* __restrict__ pm,
                                                 const double* __restrict__ Ld,
                                                 const float* __restrict__ A0,
                                                 double* __restrict__ llt,
                                                 double* __restrict__ ll0) {
  __shared__ float spm[NN];
  __shared__ double sL[NN];
  int j = threadIdx.x;
  int blk = blockIdx.x;
  if (blk < T_STEPS * BB) {
    int b = blk & 3;
    sL[j] = Ld[b * NN + j];
    spm[j] = pm[blk * NN + j];
    __syncthreads();
    float pmj = spm[j];
    double acc = 0.0;
    #pragma unroll 4
    for (int i = 0; i < NN; i++) {
      float x = __fmul_rn(spm[i], pmj);
      float sgm = 1.0f / (1.0f + expf(-x));   // XLA logistic = 1/(1+exp(-x))
      acc += (double)sgm * sL[i];
    }
    llt[blk * NN + j] = acc;
  } else {
    int b = blk - T_STEPS * BB;
    sL[j] = Ld[b * NN + j];
    __syncthreads();
    double acc = 0.0;
    #pragma unroll 4
    for (int i = 0; i < NN; i++) {
      acc += (double)A0[i * NN + j] * sL[i];
    }
    ll0[b * NN + j] = acc;
  }
}

// ---------------- Kernel D: sequential MCMC accept chain (1 block) ----------
__global__ __launch_bounds__(512) void chain_kernel(const double* __restrict__ llt,
                                                    const double* __restrict__ ll0,
                                                    const float* __restrict__ uacc,
                                                    int* __restrict__ counts) {
  __shared__ double red[8];     // per-wave partials
  __shared__ int scnt[BB * (T_STEPS + 1)];
  __shared__ int sstate[BB];
  int j = threadIdx.x;
  int lane = j & 63;
  int wid = j >> 6;
  for (int s = j; s < BB * (T_STEPS + 1); s += NN) scnt[s] = 0;
  if (j < BB) sstate[j] = -1;
  double llcur[BB];
  for (int b = 0; b < BB; b++) llcur[b] = ll0[b * NN + j];
  __syncthreads();

  for (int t = 0; t < T_STEPS; t++) {
    double lltv[BB];
    double diff = 0.0;
    #pragma unroll
    for (int b = 0; b < BB; b++) {
      lltv[b] = llt[(t * BB + b) * NN + j];
      diff += lltv[b] - llcur[b];
    }
    double e = exp(diff);
    e = fmin(e, 1.0);
    // wave reduce (width 64)
    #pragma unroll
    for (int off = 32; off > 0; off >>= 1) e += __shfl_down(e, off, 64);
    if (lane == 0) red[wid] = e;
    __syncthreads();
    double tot = 0.0;
    #pragma unroll
    for (int w = 0; w < 8; w++) tot += red[w];   // identical on all threads
    double ratio = tot * (1.0 / NN);
    #pragma unroll
    for (int b = 0; b < BB; b++) {
      if ((double)uacc[t * 4 + b] < ratio) {
        llcur[b] = lltv[b];
        if (j == 0) sstate[b] = t;
      }
    }
    if (j == 0) {
      for (int b = 0; b < BB; b++) scnt[b * (T_STEPS + 1) + (sstate[b] + 1)]++;
    }
    __syncthreads();  // red[] reuse next step
  }
  for (int s = j; s < BB * (T_STEPS + 1); s += NN) counts[s] = scnt[s];
}

// ---------------- Kernel E: acc = sum_states count * A_state / num_samples --
__global__ __launch_bounds__(512) void out_kernel(const float* __restrict__ pm,
                                                  const float* __restrict__ A0,
                                                  const int* __restrict__ counts,
                                                  float* __restrict__ out) {
  __shared__ int scnt[T_STEPS + 1];
  int b = blockIdx.x >> 9;
  int i = blockIdx.x & 511;
  int j = threadIdx.x;
  if (j < T_STEPS + 1) scnt[j] = counts[b * (T_STEPS + 1) + j];
  __syncthreads();
  float r = (float)scnt[0] * A0[i * NN + j];
  for (int t = 0; t < T_STEPS; t++) {
    int c = scnt[t + 1];
    if (c) {
      float x = __fmul_rn(pm[(t * BB + b) * NN + i], pm[(t * BB + b) * NN + j]);
      float sgm = 1.0f / (1.0f + expf(-x));
      r += (float)c * sgm;
    }
  }
  out[(b * NN + i) * NN + j] = r / 100.0f;
}

extern "C" void kernel_launch(void* const* d_in, const int* in_sizes, int n_in,
                              void* d_out, int out_size, void* d_ws, size_t ws_size,
                              hipStream_t stream) {
  const float* mu  = (const float*)d_in[0];
  const float* sig = (const float*)d_in[1];
  const float* pi  = (const float*)d_in[2];
  const float* A0  = (const float*)d_in[3];
  // d_in[4] = num_samples (100, fixed by setup_inputs)

  char* ws = (char*)d_ws;
  double* llt  = (double*)(ws);                    // 100*4*512*8 = 1,638,400
  double* ll0  = (double*)(ws + 1638400);          // 16,384
  double* Ld   = (double*)(ws + 1655296);          // 16,384
  float*  pm   = (float*)(ws + 1671680);           // 819,200
  float*  sm   = (float*)(ws + 2490880);           // 8,192
  float*  ssv  = (float*)(ws + 2499072);           // 8,192
  float*  uacc = (float*)(ws + 2507264);           // 1,600
  int*    cnts = (int*)(ws + 2508864);             // 1,616
  float*  out  = (float*)d_out;

  prep_kernel<<<8, 256, 0, stream>>>(mu, sig, pi, sm, ssv, Ld);
  rng_kernel<<<(T_STEPS * BB * NN + 255) / 256, 256, 0, stream>>>(sm, ssv, pm, uacc);
  ll_kernel<<<T_STEPS * BB + BB, 512, 0, stream>>>(pm, Ld, A0, llt, ll0);
  chain_kernel<<<1, 512, 0, stream>>>(llt, ll0, uacc, cnts);
  out_kernel<<<BB * NN, 512, 0, stream>>>(pm, A0, cnts, out);
}

// Round 3
// 272.636 us; speedup vs baseline: 1.1189x; 1.1189x over previous
//
#include <hip/hip_runtime.h>
#include <stdint.h>

#define T_STEPS 100
#define BB 4
#define NN 512
#define KK 10

// ---------------- threefry2x32 (JAX-compatible, 20 rounds) ----------------
__device__ __forceinline__ uint32_t rotl32(uint32_t v, int d) {
  return (v << d) | (v >> (32 - d));
}

__device__ __forceinline__ void tf2x32(uint32_t k0, uint32_t k1,
                                       uint32_t& x0, uint32_t& x1) {
  uint32_t k2 = k0 ^ k1 ^ 0x1BD11BDAu;
  x0 += k0; x1 += k1;
#define TFR(r) { x0 += x1; x1 = rotl32(x1, r); x1 ^= x0; }
  TFR(13) TFR(15) TFR(26) TFR(6)   x0 += k1; x1 += k2 + 1u;
  TFR(17) TFR(29) TFR(16) TFR(24)  x0 += k2; x1 += k0 + 2u;
  TFR(13) TFR(15) TFR(26) TFR(6)   x0 += k0; x1 += k1 + 3u;
  TFR(17) TFR(29) TFR(16) TFR(24)  x0 += k1; x1 += k2 + 4u;
  TFR(13) TFR(15) TFR(26) TFR(6)   x0 += k2; x1 += k0 + 5u;
#undef TFR
}

__device__ __forceinline__ float bits_to_u01(uint32_t bits) {
  return __fsub_rn(__uint_as_float((bits >> 9) | 0x3f800000u), 1.0f);
}

// XLA ErfInv32 (Giles), w = -log((1-x)(1+x)) exactly as ElementalIrEmitter
__device__ __forceinline__ float erfinv_f32(float x) {
  float w = -logf(__fmul_rn(__fsub_rn(1.0f, x), __fadd_rn(1.0f, x)));
  float p;
  if (w < 5.0f) {
    w = __fsub_rn(w, 2.5f);
    p = 2.81022636e-08f;
    p = __fadd_rn(__fmul_rn(p, w), 3.43273939e-07f);
    p = __fadd_rn(__fmul_rn(p, w), -3.5233877e-06f);
    p = __fadd_rn(__fmul_rn(p, w), -4.39150654e-06f);
    p = __fadd_rn(__fmul_rn(p, w), 0.00021858087f);
    p = __fadd_rn(__fmul_rn(p, w), -0.00125372503f);
    p = __fadd_rn(__fmul_rn(p, w), -0.00417768164f);
    p = __fadd_rn(__fmul_rn(p, w), 0.246640727f);
    p = __fadd_rn(__fmul_rn(p, w), 1.50140941f);
  } else {
    w = __fsub_rn(sqrtf(w), 3.0f);
    p = -0.000200214257f;
    p = __fadd_rn(__fmul_rn(p, w), 0.000100950558f);
    p = __fadd_rn(__fmul_rn(p, w), 0.00134934322f);
    p = __fadd_rn(__fmul_rn(p, w), -0.00367342844f);
    p = __fadd_rn(__fmul_rn(p, w), 0.00573950773f);
    p = __fadd_rn(__fmul_rn(p, w), -0.0076224613f);
    p = __fadd_rn(__fmul_rn(p, w), 0.00943887047f);
    p = __fadd_rn(__fmul_rn(p, w), 1.00167406f);
    p = __fadd_rn(__fmul_rn(p, w), 2.83297682f);
  }
  return __fmul_rn(p, x);
}

// ---------------- Kernel A: softmax-mixture mean/std + L = log(ep)-log(1-ep) --
__global__ void prep_kernel(const float* __restrict__ mu,
                            const float* __restrict__ sig,
                            const float* __restrict__ pi,
                            float* __restrict__ sm, float* __restrict__ ss,
                            double* __restrict__ Ld) {
  int m = blockIdx.x * blockDim.x + threadIdx.x;
  if (m >= BB * NN) return;
  const float* pp = pi + m * KK;
  float mx = pp[0];
  for (int k = 1; k < KK; k++) mx = fmaxf(mx, pp[k]);
  float e[KK]; float s = 0.0f;
  for (int k = 0; k < KK; k++) { e[k] = expf(__fsub_rn(pp[k], mx)); s = __fadd_rn(s, e[k]); }
  float smv = 0.0f, ssv = 0.0f, eps = 0.0f;
  for (int k = 0; k < KK; k++) {
    float p = e[k] / s;
    smv = __fadd_rn(smv, __fmul_rn(p, mu[m * KK + k]));
    ssv = __fadd_rn(ssv, __fmul_rn(p, sig[m * KK + k]));
    eps = __fadd_rn(eps, pp[k]);
  }
  sm[m] = smv; ss[m] = ssv;
  float ep = fminf(fmaxf(eps, 1e-8f), 1.0f);
  float lep = logf(ep);
  float l1 = logf(__fsub_rn(1.0f, ep));
  Ld[m] = (double)lep - (double)l1;
}

// -------- Kernel B: JAX partitionable-threefry RNG -> pm table + uniforms ----
__global__ void rng_kernel(const float* __restrict__ sm,
                           const float* __restrict__ ss,
                           float* __restrict__ pm, float* __restrict__ uacc) {
  int id = blockIdx.x * blockDim.x + threadIdx.x;
  if (id >= T_STEPS * BB * NN) return;
  int t = id >> 11;        // /2048
  int m = id & 2047;       // b*512+n

  // kk = fold_in(key(42), t) = threefry([0,42], [0,t])
  uint32_t kk0 = 0u, kk1 = (uint32_t)t;
  tf2x32(0u, 42u, kk0, kk1);
  // partitionable split (foldlike): k_noise = enc_kk(0,0), k_unif = enc_kk(0,1)
  uint32_t n0 = 0u, n1 = 0u; tf2x32(kk0, kk1, n0, n1);
  // partitionable random_bits(32): bits[m] = x0^x1 of enc_key(hi=0, lo=m)
  uint32_t y0 = 0u, y1 = (uint32_t)m;
  tf2x32(n0, n1, y0, y1);
  uint32_t bits = y0 ^ y1;

  float u01 = bits_to_u01(bits);
  const float lo = -0.99999994f;  // nextafter(-1,0) f32; span rounds to 2.0f
  float u = fmaxf(lo, __fadd_rn(__fmul_rn(u01, 2.0f), lo));
  float z = __fmul_rn(1.41421356237309515f, erfinv_f32(u));
  pm[id] = __fadd_rn(sm[m], __fmul_rn(z, ss[m]));

  if (m < 4) {
    uint32_t u0 = 0u, u1 = 1u; tf2x32(kk0, kk1, u0, u1);     // k_unif
    uint32_t c0 = 0u, c1 = (uint32_t)m;
    tf2x32(u0, u1, c0, c1);
    uacc[t * 4 + m] = bits_to_u01(c0 ^ c1);
  }
}

// ---------------- Kernel C: llt[t][b][j] = sum_i sigmoid(pm_i*pm_j)*L[b,i] ---
__global__ __launch_bounds__(512) void ll_kernel(const float* __restrict__ pm,
                                                 const double* __restrict__ Ld,
                                                 const float* __restrict__ A0,
                                                 double* __restrict__ llt,
                                                 double* __restrict__ ll0) {
  __shared__ float spm[NN];
  __shared__ double sL[NN];
  int j = threadIdx.x;
  int blk = blockIdx.x;
  if (blk < T_STEPS * BB) {
    int b = blk & 3;
    sL[j] = Ld[b * NN + j];
    spm[j] = pm[blk * NN + j];
    __syncthreads();
    float pmj = spm[j];
    double acc = 0.0;
    #pragma unroll 4
    for (int i = 0; i < NN; i++) {
      float x = __fmul_rn(spm[i], pmj);
      float sgm = 1.0f / (1.0f + expf(-x));   // XLA logistic = 1/(1+exp(-x))
      acc += (double)sgm * sL[i];
    }
    llt[blk * NN + j] = acc;
  } else {
    int b = blk - T_STEPS * BB;
    sL[j] = Ld[b * NN + j];
    __syncthreads();
    double acc = 0.0;
    #pragma unroll 4
    for (int i = 0; i < NN; i++) {
      acc += (double)A0[i * NN + j] * sL[i];
    }
    ll0[b * NN + j] = acc;
  }
}

// ------- Kernel D: sequential MCMC accept chain (SINGLE WAVE, 64 lanes) -----
// lane owns j = lane*8 + q, q = 0..7.  All state in registers; llt tiles
// double-buffered (A/B named regs, static indices only); prefetch t+1 during
// step t.  Reduce = 6-stage f64 shfl_xor butterfly (bit-identical per lane).
#define CHAIN_LOAD(BUF, T)                                                   \
  {                                                                          \
    _Pragma("unroll")                                                        \
    for (int b = 0; b < 4; b++) {                                            \
      _Pragma("unroll")                                                      \
      for (int p = 0; p < 4; p++) {                                          \
        double2 tmp = llt2[((T) * 4 + b) * 256 + lane * 4 + p];              \
        BUF[b * 8 + 2 * p] = tmp.x;                                          \
        BUF[b * 8 + 2 * p + 1] = tmp.y;                                      \
      }                                                                      \
    }                                                                        \
  }

#define CHAIN_STEP(BUF, T)                                                   \
  {                                                                          \
    float4 ua = sua[T];                                                      \
    double ps = 0.0;                                                         \
    _Pragma("unroll")                                                        \
    for (int q = 0; q < 8; q++) {                                            \
      double d = (BUF[q] - cur[q]) + (BUF[8 + q] - cur[8 + q]) +             \
                 (BUF[16 + q] - cur[16 + q]) + (BUF[24 + q] - cur[24 + q]);  \
      float e = fminf(expf((float)d), 1.0f);                                 \
      ps += (double)e;                                                       \
    }                                                                        \
    _Pragma("unroll")                                                        \
    for (int off = 32; off > 0; off >>= 1) ps += __shfl_xor(ps, off, 64);    \
    double ratio = ps * (1.0 / 512.0);                                       \
    if ((double)ua.x < ratio) {                                              \
      st.x = (T);                                                            \
      _Pragma("unroll") for (int q = 0; q < 8; q++) cur[q] = BUF[q];         \
    }                                                                        \
    if ((double)ua.y < ratio) {                                              \
      st.y = (T);                                                            \
      _Pragma("unroll") for (int q = 0; q < 8; q++) cur[8 + q] = BUF[8 + q]; \
    }                                                                        \
    if ((double)ua.z < ratio) {                                              \
      st.z = (T);                                                            \
      _Pragma("unroll") for (int q = 0; q < 8; q++)                          \
        cur[16 + q] = BUF[16 + q];                                           \
    }                                                                        \
    if ((double)ua.w < ratio) {                                              \
      st.w = (T);                                                            \
      _Pragma("unroll") for (int q = 0; q < 8; q++)                          \
        cur[24 + q] = BUF[24 + q];                                           \
    }                                                                        \
    if (lane == 0) sst[T] = st;                                              \
  }

__global__ __launch_bounds__(64) void chain_kernel(const double* __restrict__ llt,
                                                   const double* __restrict__ ll0,
                                                   const float* __restrict__ uacc,
                                                   int* __restrict__ counts) {
  __shared__ float4 sua[T_STEPS];
  __shared__ int4 sst[T_STEPS];
  __shared__ int scnt[BB * (T_STEPS + 1)];
  int lane = threadIdx.x;

  for (int t = lane; t < T_STEPS; t += 64) {
    sua[t] = make_float4(uacc[4 * t], uacc[4 * t + 1],
                         uacc[4 * t + 2], uacc[4 * t + 3]);
  }

  double cur[32];
  #pragma unroll
  for (int b = 0; b < 4; b++) {
    #pragma unroll
    for (int q = 0; q < 8; q++) cur[b * 8 + q] = ll0[b * 512 + lane * 8 + q];
  }
  int4 st = make_int4(-1, -1, -1, -1);

  const double2* llt2 = (const double2*)llt;
  double A[32], B[32];
  CHAIN_LOAD(A, 0)

  for (int t = 0; t < T_STEPS; t += 2) {
    CHAIN_LOAD(B, t + 1)        // prefetch t+1 while computing t
    CHAIN_STEP(A, t)
    if (t + 2 < T_STEPS) CHAIN_LOAD(A, t + 2)  // prefetch t+2 during t+1
    CHAIN_STEP(B, t + 1)
  }

  __syncthreads();  // single wave: cheap; orders sst writes before reads
  for (int s = lane; s < BB * (T_STEPS + 1); s += 64) scnt[s] = 0;
  __syncthreads();
  for (int t = lane; t < T_STEPS; t += 64) {
    int4 s4 = sst[t];
    atomicAdd(&scnt[0 * (T_STEPS + 1) + s4.x + 1], 1);
    atomicAdd(&scnt[1 * (T_STEPS + 1) + s4.y + 1], 1);
    atomicAdd(&scnt[2 * (T_STEPS + 1) + s4.z + 1], 1);
    atomicAdd(&scnt[3 * (T_STEPS + 1) + s4.w + 1], 1);
  }
  __syncthreads();
  for (int s = lane; s < BB * (T_STEPS + 1); s += 64) counts[s] = scnt[s];
}

// ---------------- Kernel E: acc = sum_states count * A_state / num_samples --
__global__ __launch_bounds__(512) void out_kernel(const float* __restrict__ pm,
                                                  const float* __restrict__ A0,
                                                  const int* __restrict__ counts,
                                                  float* __restrict__ out) {
  __shared__ int scnt[T_STEPS + 1];
  int b = blockIdx.x >> 9;
  int i = blockIdx.x & 511;
  int j = threadIdx.x;
  if (j < T_STEPS + 1) scnt[j] = counts[b * (T_STEPS + 1) + j];
  __syncthreads();
  float r = (float)scnt[0] * A0[i * NN + j];
  for (int t = 0; t < T_STEPS; t++) {
    int c = scnt[t + 1];
    if (c) {
      float x = __fmul_rn(pm[(t * BB + b) * NN + i], pm[(t * BB + b) * NN + j]);
      float sgm = 1.0f / (1.0f + expf(-x));
      r += (float)c * sgm;
    }
  }
  out[(b * NN + i) * NN + j] = r / 100.0f;
}

extern "C" void kernel_launch(void* const* d_in, const int* in_sizes, int n_in,
                              void* d_out, int out_size, void* d_ws, size_t ws_size,
                              hipStream_t stream) {
  const float* mu  = (const float*)d_in[0];
  const float* sig = (const float*)d_in[1];
  const float* pi  = (const float*)d_in[2];
  const float* A0  = (const float*)d_in[3];
  // d_in[4] = num_samples (100, fixed by setup_inputs)

  char* ws = (char*)d_ws;
  double* llt  = (double*)(ws);                    // 100*4*512*8 = 1,638,400
  double* ll0  = (double*)(ws + 1638400);          // 16,384
  double* Ld   = (double*)(ws + 1655296);          // 16,384
  float*  pm   = (float*)(ws + 1671680);           // 819,200
  float*  sm   = (float*)(ws + 2490880);           // 8,192
  float*  ssv  = (float*)(ws + 2499072);           // 8,192
  float*  uacc = (float*)(ws + 2507264);           // 1,600
  int*    cnts = (int*)(ws + 2508864);             // 1,616
  float*  out  = (float*)d_out;

  prep_kernel<<<8, 256, 0, stream>>>(mu, sig, pi, sm, ssv, Ld);
  rng_kernel<<<(T_STEPS * BB * NN + 255) / 256, 256, 0, stream>>>(sm, ssv, pm, uacc);
  ll_kernel<<<T_STEPS * BB + BB, 512, 0, stream>>>(pm, Ld, A0, llt, ll0);
  chain_kernel<<<1, 64, 0, stream>>>(llt, ll0, uacc, cnts);
  out_kernel<<<BB * NN, 512, 0, stream>>>(pm, A0, cnts, out);
}

// Round 4
// 155.879 us; speedup vs baseline: 1.9570x; 1.7490x over previous
//
#include <hip/hip_runtime.h>
#include <stdint.h>

#define T_STEPS 100
#define BB 4
#define NN 512
#define KK 10
#define TBTOT (T_STEPS * BB)        // 400
#define LLT_ELT ((size_t)TBTOT * NN) // 204800 doubles

// ---------------- threefry2x32 (JAX-compatible, 20 rounds) ----------------
__device__ __forceinline__ uint32_t rotl32(uint32_t v, int d) {
  return (v << d) | (v >> (32 - d));
}

__device__ __forceinline__ void tf2x32(uint32_t k0, uint32_t k1,
                                       uint32_t& x0, uint32_t& x1) {
  uint32_t k2 = k0 ^ k1 ^ 0x1BD11BDAu;
  x0 += k0; x1 += k1;
#define TFR(r) { x0 += x1; x1 = rotl32(x1, r); x1 ^= x0; }
  TFR(13) TFR(15) TFR(26) TFR(6)   x0 += k1; x1 += k2 + 1u;
  TFR(17) TFR(29) TFR(16) TFR(24)  x0 += k2; x1 += k0 + 2u;
  TFR(13) TFR(15) TFR(26) TFR(6)   x0 += k0; x1 += k1 + 3u;
  TFR(17) TFR(29) TFR(16) TFR(24)  x0 += k1; x1 += k2 + 4u;
  TFR(13) TFR(15) TFR(26) TFR(6)   x0 += k2; x1 += k0 + 5u;
#undef TFR
}

__device__ __forceinline__ float bits_to_u01(uint32_t bits) {
  return __fsub_rn(__uint_as_float((bits >> 9) | 0x3f800000u), 1.0f);
}

// XLA ErfInv32 (Giles), w = -log((1-x)(1+x)) exactly as ElementalIrEmitter
__device__ __forceinline__ float erfinv_f32(float x) {
  float w = -logf(__fmul_rn(__fsub_rn(1.0f, x), __fadd_rn(1.0f, x)));
  float p;
  if (w < 5.0f) {
    w = __fsub_rn(w, 2.5f);
    p = 2.81022636e-08f;
    p = __fadd_rn(__fmul_rn(p, w), 3.43273939e-07f);
    p = __fadd_rn(__fmul_rn(p, w), -3.5233877e-06f);
    p = __fadd_rn(__fmul_rn(p, w), -4.39150654e-06f);
    p = __fadd_rn(__fmul_rn(p, w), 0.00021858087f);
    p = __fadd_rn(__fmul_rn(p, w), -0.00125372503f);
    p = __fadd_rn(__fmul_rn(p, w), -0.00417768164f);
    p = __fadd_rn(__fmul_rn(p, w), 0.246640727f);
    p = __fadd_rn(__fmul_rn(p, w), 1.50140941f);
  } else {
    w = __fsub_rn(sqrtf(w), 3.0f);
    p = -0.000200214257f;
    p = __fadd_rn(__fmul_rn(p, w), 0.000100950558f);
    p = __fadd_rn(__fmul_rn(p, w), 0.00134934322f);
    p = __fadd_rn(__fmul_rn(p, w), -0.00367342844f);
    p = __fadd_rn(__fmul_rn(p, w), 0.00573950773f);
    p = __fadd_rn(__fmul_rn(p, w), -0.0076224613f);
    p = __fadd_rn(__fmul_rn(p, w), 0.00943887047f);
    p = __fadd_rn(__fmul_rn(p, w), 1.00167406f);
    p = __fadd_rn(__fmul_rn(p, w), 2.83297682f);
  }
  return __fmul_rn(p, x);
}

// fast sigmoid: 1/(1+exp(-x)) via native exp + native rcp (~1-2 ulp)
__device__ __forceinline__ float fast_sigmoid(float x) {
  float e = __expf(-x);
  return __builtin_amdgcn_rcpf(__fadd_rn(1.0f, e));
}

// ---------------- Kernel A: softmax-mixture mean/std + L(f32) ---------------
__global__ void prep_kernel(const float* __restrict__ mu,
                            const float* __restrict__ sig,
                            const float* __restrict__ pi,
                            float* __restrict__ sm, float* __restrict__ ss,
                            float* __restrict__ Lf) {
  int m = blockIdx.x * blockDim.x + threadIdx.x;
  if (m >= BB * NN) return;
  const float* pp = pi + m * KK;
  float mx = pp[0];
  for (int k = 1; k < KK; k++) mx = fmaxf(mx, pp[k]);
  float e[KK]; float s = 0.0f;
  for (int k = 0; k < KK; k++) { e[k] = expf(__fsub_rn(pp[k], mx)); s = __fadd_rn(s, e[k]); }
  float smv = 0.0f, ssv = 0.0f, eps = 0.0f;
  for (int k = 0; k < KK; k++) {
    float p = e[k] / s;
    smv = __fadd_rn(smv, __fmul_rn(p, mu[m * KK + k]));
    ssv = __fadd_rn(ssv, __fmul_rn(p, sig[m * KK + k]));
    eps = __fadd_rn(eps, pp[k]);
  }
  sm[m] = smv; ss[m] = ssv;
  float ep = fminf(fmaxf(eps, 1e-8f), 1.0f);
  float lep = logf(ep);
  float l1 = logf(__fsub_rn(1.0f, ep));
  Lf[m] = (float)((double)lep - (double)l1);
}

// -------- Kernel B: JAX partitionable-threefry RNG -> pm table + uniforms ----
__global__ void rng_kernel(const float* __restrict__ sm,
                           const float* __restrict__ ss,
                           float* __restrict__ pm, float* __restrict__ uacc) {
  int id = blockIdx.x * blockDim.x + threadIdx.x;
  if (id >= T_STEPS * BB * NN) return;
  int t = id >> 11;        // /2048
  int m = id & 2047;       // b*512+n

  uint32_t kk0 = 0u, kk1 = (uint32_t)t;
  tf2x32(0u, 42u, kk0, kk1);
  uint32_t n0 = 0u, n1 = 0u; tf2x32(kk0, kk1, n0, n1);   // k_noise
  uint32_t y0 = 0u, y1 = (uint32_t)m;
  tf2x32(n0, n1, y0, y1);
  uint32_t bits = y0 ^ y1;

  float u01 = bits_to_u01(bits);
  const float lo = -0.99999994f;  // nextafter(-1,0) f32; span rounds to 2.0f
  float u = fmaxf(lo, __fadd_rn(__fmul_rn(u01, 2.0f), lo));
  float z = __fmul_rn(1.41421356237309515f, erfinv_f32(u));
  pm[id] = __fadd_rn(sm[m], __fmul_rn(z, ss[m]));

  if (m < 4) {
    uint32_t u0 = 0u, u1 = 1u; tf2x32(kk0, kk1, u0, u1); // k_unif
    uint32_t c0 = 0u, c1 = (uint32_t)m;
    tf2x32(u0, u1, c0, c1);
    uacc[t * 4 + m] = bits_to_u01(c0 ^ c1);
  }
}

// ------- Kernel C: partial llt[t][b][j] = sum_{i in chunk} sgm(pm_i pm_j)*L[b,i]
template <int SPLIT>
__global__ __launch_bounds__(512) void ll_kernel(const float* __restrict__ pm,
                                                 const float* __restrict__ Lf,
                                                 const float* __restrict__ A0,
                                                 double* __restrict__ llt_p,
                                                 double* __restrict__ ll0_p) {
  constexpr int CH = NN / SPLIT;
  __shared__ float spm[CH];
  __shared__ float sLc[CH];
  int j = threadIdx.x;
  int bi = blockIdx.x;
  if (bi < TBTOT * SPLIT) {
    int tb = bi / SPLIT;
    int s = bi - tb * SPLIT;
    int b = tb & 3;
    int i0 = s * CH;
    if (j < CH) {
      spm[j] = pm[tb * NN + i0 + j];
      sLc[j] = Lf[b * NN + i0 + j];
    }
    float pmj = pm[tb * NN + j];
    __syncthreads();
    double acc = 0.0;
    #pragma unroll 8
    for (int i = 0; i < CH; i += 2) {
      float x0 = __fmul_rn(spm[i], pmj);
      float x1 = __fmul_rn(spm[i + 1], pmj);
      float t0 = __fmul_rn(fast_sigmoid(x0), sLc[i]);
      float t1 = __fmul_rn(fast_sigmoid(x1), sLc[i + 1]);
      acc += (double)__fadd_rn(t0, t1);
    }
    llt_p[(size_t)s * LLT_ELT + (size_t)tb * NN + j] = acc;
  } else {
    int bi2 = bi - TBTOT * SPLIT;
    int b = bi2 / SPLIT;
    int s = bi2 - b * SPLIT;
    int i0 = s * CH;
    if (j < CH) sLc[j] = Lf[b * NN + i0 + j];
    __syncthreads();
    double acc = 0.0;
    #pragma unroll 4
    for (int i = 0; i < CH; i++) {
      acc += (double)A0[(size_t)(i0 + i) * NN + j] * (double)sLc[i];
    }
    ll0_p[s * (BB * NN) + b * NN + j] = acc;
  }
}

// ------- Kernel C2: deterministic combine of partials ------------------------
template <int SPLIT>
__global__ __launch_bounds__(512) void combine_kernel(const double* __restrict__ llt_p,
                                                      const double* __restrict__ ll0_p,
                                                      double* __restrict__ llt,
                                                      double* __restrict__ ll0) {
  int bi = blockIdx.x;
  int j = threadIdx.x;
  if (bi < TBTOT) {
    size_t idx = (size_t)bi * NN + j;
    double a = llt_p[idx];
    #pragma unroll
    for (int s = 1; s < SPLIT; s++) a += llt_p[(size_t)s * LLT_ELT + idx];
    llt[idx] = a;
  } else {
    int idx = (bi - TBTOT) * NN + j;
    double a = ll0_p[idx];
    #pragma unroll
    for (int s = 1; s < SPLIT; s++) a += ll0_p[s * (BB * NN) + idx];
    ll0[idx] = a;
  }
}

// ------- Kernel D: sequential MCMC chain, 256 threads (4 waves) -------------
// lane g owns j = 2g, 2g+1; tiles double-buffered in registers (static idx);
// f32 exp + f32 butterfly (ratio is f32 in the reference); 1 barrier/step with
// parity-slotted LDS partials.
#define CH_LOAD(BUF, T)                                                      \
  {                                                                          \
    _Pragma("unroll")                                                        \
    for (int b = 0; b < 4; b++)                                              \
      BUF[b] = llt2[((size_t)(T) * 4 + b) * 256 + g];                        \
  }

#define CH_STEP(BUF, T)                                                      \
  {                                                                          \
    float4 ua = sua[T];                                                      \
    double d0 = (BUF[0].x - cur[0].x) + (BUF[1].x - cur[1].x) +              \
                (BUF[2].x - cur[2].x) + (BUF[3].x - cur[3].x);               \
    double d1 = (BUF[0].y - cur[0].y) + (BUF[1].y - cur[1].y) +              \
                (BUF[2].y - cur[2].y) + (BUF[3].y - cur[3].y);               \
    float ps = __fadd_rn(fminf(__expf((float)d0), 1.0f),                     \
                         fminf(__expf((float)d1), 1.0f));                    \
    _Pragma("unroll")                                                        \
    for (int off = 32; off > 0; off >>= 1) ps += __shfl_xor(ps, off, 64);    \
    if ((g & 63) == 0) red[(T) & 1][g >> 6] = ps;                            \
    __syncthreads();                                                         \
    float ratio = (red[(T) & 1][0] + red[(T) & 1][1] + red[(T) & 1][2] +     \
                   red[(T) & 1][3]) * (1.0f / 512.0f);                       \
    if (ua.x < ratio) { st.x = (T); cur[0] = BUF[0]; }                       \
    if (ua.y < ratio) { st.y = (T); cur[1] = BUF[1]; }                       \
    if (ua.z < ratio) { st.z = (T); cur[2] = BUF[2]; }                       \
    if (ua.w < ratio) { st.w = (T); cur[3] = BUF[3]; }                       \
    if (g == 0) sst[T] = st;                                                 \
  }

__global__ __launch_bounds__(256, 1) void chain_kernel(const double* __restrict__ llt,
                                                       const double* __restrict__ ll0,
                                                       const float* __restrict__ uacc,
                                                       int* __restrict__ counts) {
  __shared__ float4 sua[T_STEPS];
  __shared__ int4 sst[T_STEPS];
  __shared__ int scnt[BB * (T_STEPS + 1)];
  __shared__ float red[2][4];
  int g = threadIdx.x;

  for (int t = g; t < T_STEPS; t += 256) {
    sua[t] = make_float4(uacc[4 * t], uacc[4 * t + 1],
                         uacc[4 * t + 2], uacc[4 * t + 3]);
  }

  const double2* llt2 = (const double2*)llt;
  const double2* ll02 = (const double2*)ll0;
  double2 cur[4];
  #pragma unroll
  for (int b = 0; b < 4; b++) cur[b] = ll02[b * 256 + g];
  int4 st = make_int4(-1, -1, -1, -1);

  double2 A[4], B[4];
  CH_LOAD(A, 0)
  __syncthreads();  // sua ready

  for (int t = 0; t < T_STEPS; t += 2) {
    CH_LOAD(B, t + 1)                          // prefetch t+1 during step t
    CH_STEP(A, t)
    if (t + 2 < T_STEPS) CH_LOAD(A, t + 2)     // prefetch t+2 during step t+1
    CH_STEP(B, t + 1)
  }

  __syncthreads();
  for (int s = g; s < BB * (T_STEPS + 1); s += 256) scnt[s] = 0;
  __syncthreads();
  for (int t = g; t < T_STEPS; t += 256) {
    int4 s4 = sst[t];
    atomicAdd(&scnt[0 * (T_STEPS + 1) + s4.x + 1], 1);
    atomicAdd(&scnt[1 * (T_STEPS + 1) + s4.y + 1], 1);
    atomicAdd(&scnt[2 * (T_STEPS + 1) + s4.z + 1], 1);
    atomicAdd(&scnt[3 * (T_STEPS + 1) + s4.w + 1], 1);
  }
  __syncthreads();
  for (int s = g; s < BB * (T_STEPS + 1); s += 256) counts[s] = scnt[s];
}

// ---------------- Kernel E: acc = sum_states count * A_state / num_samples --
__global__ __launch_bounds__(512) void out_kernel(const float* __restrict__ pm,
                                                  const float* __restrict__ A0,
                                                  const int* __restrict__ counts,
                                                  float* __restrict__ out) {
  __shared__ int scnt[T_STEPS + 1];
  int b = blockIdx.x >> 9;
  int i = blockIdx.x & 511;
  int j = threadIdx.x;
  if (j < T_STEPS + 1) scnt[j] = counts[b * (T_STEPS + 1) + j];
  __syncthreads();
  float r = (float)scnt[0] * A0[(size_t)i * NN + j];
  #pragma unroll 4
  for (int t = 0; t < T_STEPS; t++) {
    int c = scnt[t + 1];
    if (c) {
      float x = __fmul_rn(pm[(size_t)(t * BB + b) * NN + i],
                          pm[(size_t)(t * BB + b) * NN + j]);
      r += (float)c * fast_sigmoid(x);
    }
  }
  out[((size_t)b * NN + i) * NN + j] = r * 0.01f;
}

extern "C" void kernel_launch(void* const* d_in, const int* in_sizes, int n_in,
                              void* d_out, int out_size, void* d_ws, size_t ws_size,
                              hipStream_t stream) {
  const float* mu  = (const float*)d_in[0];
  const float* sig = (const float*)d_in[1];
  const float* pi  = (const float*)d_in[2];
  const float* A0  = (const float*)d_in[3];

  char* ws = (char*)d_ws;
  size_t off = 0;
  auto alloc = [&](size_t bytes) -> char* {
    char* p = ws + off;
    off += (bytes + 255) & ~(size_t)255;
    return p;
  };
  double* llt  = (double*)alloc(LLT_ELT * 8);        // 1,638,400
  double* ll0  = (double*)alloc(BB * NN * 8);        // 16,384
  float*  pm   = (float*)alloc(LLT_ELT * 4);         // 819,200
  float*  Lf   = (float*)alloc(BB * NN * 4);
  float*  sm   = (float*)alloc(BB * NN * 4);
  float*  ssv  = (float*)alloc(BB * NN * 4);
  float*  uacc = (float*)alloc(T_STEPS * 4 * 4);
  int*    cnts = (int*)alloc(BB * (T_STEPS + 1) * 4);
  size_t fixed_end = off;
  float*  outp = (float*)d_out;

  // choose SPLIT by available scratch for partial buffers
  size_t part4 = 4 * LLT_ELT * 8 + 4 * BB * NN * 8 + 1024;
  size_t part2 = 2 * LLT_ELT * 8 + 2 * BB * NN * 8 + 1024;
  int split = (ws_size >= fixed_end + part4) ? 4
            : (ws_size >= fixed_end + part2) ? 2 : 1;

  double* llt_p;
  double* ll0_p;
  if (split > 1) {
    llt_p = (double*)alloc((size_t)split * LLT_ELT * 8);
    ll0_p = (double*)alloc((size_t)split * BB * NN * 8);
  } else {
    llt_p = llt;  // write directly, no combine
    ll0_p = ll0;
  }

  prep_kernel<<<8, 256, 0, stream>>>(mu, sig, pi, sm, ssv, Lf);
  rng_kernel<<<(T_STEPS * BB * NN + 255) / 256, 256, 0, stream>>>(sm, ssv, pm, uacc);
  if (split == 4) {
    ll_kernel<4><<<(TBTOT + BB) * 4, 512, 0, stream>>>(pm, Lf, A0, llt_p, ll0_p);
    combine_kernel<4><<<TBTOT + BB, 512, 0, stream>>>(llt_p, ll0_p, llt, ll0);
  } else if (split == 2) {
    ll_kernel<2><<<(TBTOT + BB) * 2, 512, 0, stream>>>(pm, Lf, A0, llt_p, ll0_p);
    combine_kernel<2><<<TBTOT + BB, 512, 0, stream>>>(llt_p, ll0_p, llt, ll0);
  } else {
    ll_kernel<1><<<TBTOT + BB, 512, 0, stream>>>(pm, Lf, A0, llt_p, ll0_p);
  }
  chain_kernel<<<1, 256, 0, stream>>>(llt, ll0, uacc, cnts);
  out_kernel<<<BB * NN, 512, 0, stream>>>(pm, A0, cnts, outp);
}

// Round 5
// 150.769 us; speedup vs baseline: 2.0233x; 1.0339x over previous
//
#include <hip/hip_runtime.h>
#include <stdint.h>

#define T_STEPS 100
#define BB 4
#define NN 512
#define KK 10
#define TBTOT (T_STEPS * BB)        // 400
#define LLT_ELT ((size_t)TBTOT * NN) // 204800 doubles

// ---------------- threefry2x32 (JAX-compatible, 20 rounds) ----------------
__device__ __forceinline__ uint32_t rotl32(uint32_t v, int d) {
  return (v << d) | (v >> (32 - d));
}

__device__ __forceinline__ void tf2x32(uint32_t k0, uint32_t k1,
                                       uint32_t& x0, uint32_t& x1) {
  uint32_t k2 = k0 ^ k1 ^ 0x1BD11BDAu;
  x0 += k0; x1 += k1;
#define TFR(r) { x0 += x1; x1 = rotl32(x1, r); x1 ^= x0; }
  TFR(13) TFR(15) TFR(26) TFR(6)   x0 += k1; x1 += k2 + 1u;
  TFR(17) TFR(29) TFR(16) TFR(24)  x0 += k2; x1 += k0 + 2u;
  TFR(13) TFR(15) TFR(26) TFR(6)   x0 += k0; x1 += k1 + 3u;
  TFR(17) TFR(29) TFR(16) TFR(24)  x0 += k1; x1 += k2 + 4u;
  TFR(13) TFR(15) TFR(26) TFR(6)   x0 += k2; x1 += k0 + 5u;
#undef TFR
}

__device__ __forceinline__ float bits_to_u01(uint32_t bits) {
  return __fsub_rn(__uint_as_float((bits >> 9) | 0x3f800000u), 1.0f);
}

// XLA ErfInv32 (Giles), w = -log((1-x)(1+x)) exactly as ElementalIrEmitter
__device__ __forceinline__ float erfinv_f32(float x) {
  float w = -logf(__fmul_rn(__fsub_rn(1.0f, x), __fadd_rn(1.0f, x)));
  float p;
  if (w < 5.0f) {
    w = __fsub_rn(w, 2.5f);
    p = 2.81022636e-08f;
    p = __fadd_rn(__fmul_rn(p, w), 3.43273939e-07f);
    p = __fadd_rn(__fmul_rn(p, w), -3.5233877e-06f);
    p = __fadd_rn(__fmul_rn(p, w), -4.39150654e-06f);
    p = __fadd_rn(__fmul_rn(p, w), 0.00021858087f);
    p = __fadd_rn(__fmul_rn(p, w), -0.00125372503f);
    p = __fadd_rn(__fmul_rn(p, w), -0.00417768164f);
    p = __fadd_rn(__fmul_rn(p, w), 0.246640727f);
    p = __fadd_rn(__fmul_rn(p, w), 1.50140941f);
  } else {
    w = __fsub_rn(sqrtf(w), 3.0f);
    p = -0.000200214257f;
    p = __fadd_rn(__fmul_rn(p, w), 0.000100950558f);
    p = __fadd_rn(__fmul_rn(p, w), 0.00134934322f);
    p = __fadd_rn(__fmul_rn(p, w), -0.00367342844f);
    p = __fadd_rn(__fmul_rn(p, w), 0.00573950773f);
    p = __fadd_rn(__fmul_rn(p, w), -0.0076224613f);
    p = __fadd_rn(__fmul_rn(p, w), 0.00943887047f);
    p = __fadd_rn(__fmul_rn(p, w), 1.00167406f);
    p = __fadd_rn(__fmul_rn(p, w), 2.83297682f);
  }
  return __fmul_rn(p, x);
}

// fast sigmoid: 1/(1+exp(-x)) via native exp + native rcp (~1-2 ulp)
__device__ __forceinline__ float fast_sigmoid(float x) {
  float e = __expf(-x);
  return __builtin_amdgcn_rcpf(__fadd_rn(1.0f, e));
}

// ---------------- Kernel A: softmax-mixture mean/std + L(f32) ---------------
__global__ void prep_kernel(const float* __restrict__ mu,
                            const float* __restrict__ sig,
                            const float* __restrict__ pi,
                            float* __restrict__ sm, float* __restrict__ ss,
                            float* __restrict__ Lf) {
  int m = blockIdx.x * blockDim.x + threadIdx.x;
  if (m >= BB * NN) return;
  const float* pp = pi + m * KK;
  float mx = pp[0];
  for (int k = 1; k < KK; k++) mx = fmaxf(mx, pp[k]);
  float e[KK]; float s = 0.0f;
  for (int k = 0; k < KK; k++) { e[k] = expf(__fsub_rn(pp[k], mx)); s = __fadd_rn(s, e[k]); }
  float smv = 0.0f, ssv = 0.0f, eps = 0.0f;
  for (int k = 0; k < KK; k++) {
    float p = e[k] / s;
    smv = __fadd_rn(smv, __fmul_rn(p, mu[m * KK + k]));
    ssv = __fadd_rn(ssv, __fmul_rn(p, sig[m * KK + k]));
    eps = __fadd_rn(eps, pp[k]);
  }
  sm[m] = smv; ss[m] = ssv;
  float ep = fminf(fmaxf(eps, 1e-8f), 1.0f);
  float lep = logf(ep);
  float l1 = logf(__fsub_rn(1.0f, ep));
  Lf[m] = (float)((double)lep - (double)l1);
}

// -------- Kernel B: JAX partitionable-threefry RNG -> pm table + uniforms ----
__global__ void rng_kernel(const float* __restrict__ sm,
                           const float* __restrict__ ss,
                           float* __restrict__ pm, float* __restrict__ uacc) {
  int id = blockIdx.x * blockDim.x + threadIdx.x;
  if (id >= T_STEPS * BB * NN) return;
  int t = id >> 11;        // /2048
  int m = id & 2047;       // b*512+n

  uint32_t kk0 = 0u, kk1 = (uint32_t)t;
  tf2x32(0u, 42u, kk0, kk1);
  uint32_t n0 = 0u, n1 = 0u; tf2x32(kk0, kk1, n0, n1);   // k_noise
  uint32_t y0 = 0u, y1 = (uint32_t)m;
  tf2x32(n0, n1, y0, y1);
  uint32_t bits = y0 ^ y1;

  float u01 = bits_to_u01(bits);
  const float lo = -0.99999994f;  // nextafter(-1,0) f32; span rounds to 2.0f
  float u = fmaxf(lo, __fadd_rn(__fmul_rn(u01, 2.0f), lo));
  float z = __fmul_rn(1.41421356237309515f, erfinv_f32(u));
  pm[id] = __fadd_rn(sm[m], __fmul_rn(z, ss[m]));

  if (m < 4) {
    uint32_t u0 = 0u, u1 = 1u; tf2x32(kk0, kk1, u0, u1); // k_unif
    uint32_t c0 = 0u, c1 = (uint32_t)m;
    tf2x32(u0, u1, c0, c1);
    uacc[t * 4 + m] = bits_to_u01(c0 ^ c1);
  }
}

// ------- Kernel C: partial llt[t][b][j] = sum_{i in chunk} sgm(pm_i pm_j)*L[b,i]
template <int SPLIT>
__global__ __launch_bounds__(512) void ll_kernel(const float* __restrict__ pm,
                                                 const float* __restrict__ Lf,
                                                 const float* __restrict__ A0,
                                                 double* __restrict__ llt_p,
                                                 double* __restrict__ ll0_p) {
  constexpr int CH = NN / SPLIT;
  __shared__ float spm[CH];
  __shared__ float sLc[CH];
  int j = threadIdx.x;
  int bi = blockIdx.x;
  if (bi < TBTOT * SPLIT) {
    int tb = bi / SPLIT;
    int s = bi - tb * SPLIT;
    int b = tb & 3;
    int i0 = s * CH;
    if (j < CH) {
      spm[j] = pm[tb * NN + i0 + j];
      sLc[j] = Lf[b * NN + i0 + j];
    }
    float pmj = pm[tb * NN + j];
    __syncthreads();
    double acc = 0.0;
    #pragma unroll 8
    for (int i = 0; i < CH; i += 2) {
      float x0 = __fmul_rn(spm[i], pmj);
      float x1 = __fmul_rn(spm[i + 1], pmj);
      float t0 = __fmul_rn(fast_sigmoid(x0), sLc[i]);
      float t1 = __fmul_rn(fast_sigmoid(x1), sLc[i + 1]);
      acc += (double)__fadd_rn(t0, t1);
    }
    llt_p[(size_t)s * LLT_ELT + (size_t)tb * NN + j] = acc;
  } else {
    int bi2 = bi - TBTOT * SPLIT;
    int b = bi2 / SPLIT;
    int s = bi2 - b * SPLIT;
    int i0 = s * CH;
    if (j < CH) sLc[j] = Lf[b * NN + i0 + j];
    __syncthreads();
    double acc = 0.0;
    #pragma unroll 4
    for (int i = 0; i < CH; i++) {
      acc += (double)A0[(size_t)(i0 + i) * NN + j] * (double)sLc[i];
    }
    ll0_p[s * (BB * NN) + b * NN + j] = acc;
  }
}

// ------- Kernel C2: deterministic combine of partials ------------------------
template <int SPLIT>
__global__ __launch_bounds__(512) void combine_kernel(const double* __restrict__ llt_p,
                                                      const double* __restrict__ ll0_p,
                                                      double* __restrict__ llt,
                                                      double* __restrict__ ll0) {
  int bi = blockIdx.x;
  int j = threadIdx.x;
  if (bi < TBTOT) {
    size_t idx = (size_t)bi * NN + j;
    double a = llt_p[idx];
    #pragma unroll
    for (int s = 1; s < SPLIT; s++) a += llt_p[(size_t)s * LLT_ELT + idx];
    llt[idx] = a;
  } else {
    int idx = (bi - TBTOT) * NN + j;
    double a = ll0_p[idx];
    #pragma unroll
    for (int s = 1; s < SPLIT; s++) a += ll0_p[s * (BB * NN) + idx];
    ll0[idx] = a;
  }
}

// ------- Kernel D: sequential MCMC chain, 256 threads, prefetch depth 4 -----
// lane g owns j = 2g, 2g+1; 4 named register buffers (static idx only);
// load for step t+4 issues right after step t consumes its buffer -> ~3.5
// steps of HBM-latency cover.  f32 exp + f32 butterfly; 1 barrier/step with
// parity-slotted LDS partials.
#define CH_LOAD(BUF, T)                                                      \
  {                                                                          \
    _Pragma("unroll")                                                        \
    for (int b = 0; b < 4; b++)                                              \
      BUF[b] = llt2[((size_t)(T) * 4 + b) * 256 + g];                        \
  }

#define CH_STEP(BUF, T)                                                      \
  {                                                                          \
    float4 ua = sua[T];                                                      \
    double d0 = (BUF[0].x - cur[0].x) + (BUF[1].x - cur[1].x) +              \
                (BUF[2].x - cur[2].x) + (BUF[3].x - cur[3].x);               \
    double d1 = (BUF[0].y - cur[0].y) + (BUF[1].y - cur[1].y) +              \
                (BUF[2].y - cur[2].y) + (BUF[3].y - cur[3].y);               \
    float ps = __fadd_rn(fminf(__expf((float)d0), 1.0f),                     \
                         fminf(__expf((float)d1), 1.0f));                    \
    _Pragma("unroll")                                                        \
    for (int off = 32; off > 0; off >>= 1) ps += __shfl_xor(ps, off, 64);    \
    if ((g & 63) == 0) red[(T) & 1][g >> 6] = ps;                            \
    __syncthreads();                                                         \
    float ratio = (red[(T) & 1][0] + red[(T) & 1][1] + red[(T) & 1][2] +     \
                   red[(T) & 1][3]) * (1.0f / 512.0f);                       \
    if (ua.x < ratio) { st.x = (T); cur[0] = BUF[0]; }                       \
    if (ua.y < ratio) { st.y = (T); cur[1] = BUF[1]; }                       \
    if (ua.z < ratio) { st.z = (T); cur[2] = BUF[2]; }                       \
    if (ua.w < ratio) { st.w = (T); cur[3] = BUF[3]; }                       \
    if (g == 0) sst[T] = st;                                                 \
  }

__global__ __launch_bounds__(256, 1) void chain_kernel(const double* __restrict__ llt,
                                                       const double* __restrict__ ll0,
                                                       const float* __restrict__ uacc,
                                                       int* __restrict__ counts) {
  __shared__ float4 sua[T_STEPS];
  __shared__ int4 sst[T_STEPS];
  __shared__ int scnt[BB * (T_STEPS + 1)];
  __shared__ float red[2][4];
  int g = threadIdx.x;

  for (int t = g; t < T_STEPS; t += 256) {
    sua[t] = make_float4(uacc[4 * t], uacc[4 * t + 1],
                         uacc[4 * t + 2], uacc[4 * t + 3]);
  }

  const double2* llt2 = (const double2*)llt;
  const double2* ll02 = (const double2*)ll0;
  double2 cur[4];
  #pragma unroll
  for (int b = 0; b < 4; b++) cur[b] = ll02[b * 256 + g];
  int4 st = make_int4(-1, -1, -1, -1);

  double2 R0[4], R1[4], R2[4], R3[4];
  CH_LOAD(R0, 0)
  CH_LOAD(R1, 1)
  CH_LOAD(R2, 2)
  CH_LOAD(R3, 3)
  __syncthreads();  // sua ready

  for (int t = 0; t < T_STEPS; t += 4) {
    CH_STEP(R0, t)
    if (t + 4 < T_STEPS) CH_LOAD(R0, t + 4)
    CH_STEP(R1, t + 1)
    if (t + 5 < T_STEPS) CH_LOAD(R1, t + 5)
    CH_STEP(R2, t + 2)
    if (t + 6 < T_STEPS) CH_LOAD(R2, t + 6)
    CH_STEP(R3, t + 3)
    if (t + 7 < T_STEPS) CH_LOAD(R3, t + 7)
  }

  __syncthreads();
  for (int s = g; s < BB * (T_STEPS + 1); s += 256) scnt[s] = 0;
  __syncthreads();
  for (int t = g; t < T_STEPS; t += 256) {
    int4 s4 = sst[t];
    atomicAdd(&scnt[0 * (T_STEPS + 1) + s4.x + 1], 1);
    atomicAdd(&scnt[1 * (T_STEPS + 1) + s4.y + 1], 1);
    atomicAdd(&scnt[2 * (T_STEPS + 1) + s4.z + 1], 1);
    atomicAdd(&scnt[3 * (T_STEPS + 1) + s4.w + 1], 1);
  }
  __syncthreads();
  for (int s = g; s < BB * (T_STEPS + 1); s += 256) counts[s] = scnt[s];
}

// ---------------- Kernel E: acc = sum_states count * A_state / num_samples --
__global__ __launch_bounds__(512) void out_kernel(const float* __restrict__ pm,
                                                  const float* __restrict__ A0,
                                                  const int* __restrict__ counts,
                                                  float* __restrict__ out) {
  __shared__ int scnt[T_STEPS + 1];
  int b = blockIdx.x >> 9;
  int i = blockIdx.x & 511;
  int j = threadIdx.x;
  if (j < T_STEPS + 1) scnt[j] = counts[b * (T_STEPS + 1) + j];
  __syncthreads();
  float r = (float)scnt[0] * A0[(size_t)i * NN + j];
  #pragma unroll 4
  for (int t = 0; t < T_STEPS; t++) {
    int c = scnt[t + 1];
    if (c) {
      float x = __fmul_rn(pm[(size_t)(t * BB + b) * NN + i],
                          pm[(size_t)(t * BB + b) * NN + j]);
      r += (float)c * fast_sigmoid(x);
    }
  }
  out[((size_t)b * NN + i) * NN + j] = r * 0.01f;
}

extern "C" void kernel_launch(void* const* d_in, const int* in_sizes, int n_in,
                              void* d_out, int out_size, void* d_ws, size_t ws_size,
                              hipStream_t stream) {
  const float* mu  = (const float*)d_in[0];
  const float* sig = (const float*)d_in[1];
  const float* pi  = (const float*)d_in[2];
  const float* A0  = (const float*)d_in[3];

  char* ws = (char*)d_ws;
  size_t off = 0;
  auto alloc = [&](size_t bytes) -> char* {
    char* p = ws + off;
    off += (bytes + 255) & ~(size_t)255;
    return p;
  };
  double* llt  = (double*)alloc(LLT_ELT * 8);        // 1,638,400
  double* ll0  = (double*)alloc(BB * NN * 8);        // 16,384
  float*  pm   = (float*)alloc(LLT_ELT * 4);         // 819,200
  float*  Lf   = (float*)alloc(BB * NN * 4);
  float*  sm   = (float*)alloc(BB * NN * 4);
  float*  ssv  = (float*)alloc(BB * NN * 4);
  float*  uacc = (float*)alloc(T_STEPS * 4 * 4);
  int*    cnts = (int*)alloc(BB * (T_STEPS + 1) * 4);
  size_t fixed_end = off;
  float*  outp = (float*)d_out;

  // choose SPLIT by available scratch for partial buffers
  size_t part4 = 4 * LLT_ELT * 8 + 4 * BB * NN * 8 + 1024;
  size_t part2 = 2 * LLT_ELT * 8 + 2 * BB * NN * 8 + 1024;
  int split = (ws_size >= fixed_end + part4) ? 4
            : (ws_size >= fixed_end + part2) ? 2 : 1;

  double* llt_p;
  double* ll0_p;
  if (split > 1) {
    llt_p = (double*)alloc((size_t)split * LLT_ELT * 8);
    ll0_p = (double*)alloc((size_t)split * BB * NN * 8);
  } else {
    llt_p = llt;  // write directly, no combine
    ll0_p = ll0;
  }

  prep_kernel<<<8, 256, 0, stream>>>(mu, sig, pi, sm, ssv, Lf);
  rng_kernel<<<(T_STEPS * BB * NN + 255) / 256, 256, 0, stream>>>(sm, ssv, pm, uacc);
  if (split == 4) {
    ll_kernel<4><<<(TBTOT + BB) * 4, 512, 0, stream>>>(pm, Lf, A0, llt_p, ll0_p);
    combine_kernel<4><<<TBTOT + BB, 512, 0, stream>>>(llt_p, ll0_p, llt, ll0);
  } else if (split == 2) {
    ll_kernel<2><<<(TBTOT + BB) * 2, 512, 0, stream>>>(pm, Lf, A0, llt_p, ll0_p);
    combine_kernel<2><<<TBTOT + BB, 512, 0, stream>>>(llt_p, ll0_p, llt, ll0);
  } else {
    ll_kernel<1><<<TBTOT + BB, 512, 0, stream>>>(pm, Lf, A0, llt_p, ll0_p);
  }
  chain_kernel<<<1, 256, 0, stream>>>(llt, ll0, uacc, cnts);
  out_kernel<<<BB * NN, 512, 0, stream>>>(pm, A0, cnts, outp);
}

// Round 6
// 150.331 us; speedup vs baseline: 2.0292x; 1.0029x over previous
//
#include <hip/hip_runtime.h>
#include <stdint.h>

#define T_STEPS 100
#define BB 4
#define NN 512
#define KK 10
#define TBTOT (T_STEPS * BB)        // 400
#define LLT_ELT ((size_t)TBTOT * NN) // 204800 doubles

// ---------------- threefry2x32 (JAX-compatible, 20 rounds) ----------------
__device__ __forceinline__ uint32_t rotl32(uint32_t v, int d) {
  return (v << d) | (v >> (32 - d));
}

__device__ __forceinline__ void tf2x32(uint32_t k0, uint32_t k1,
                                       uint32_t& x0, uint32_t& x1) {
  uint32_t k2 = k0 ^ k1 ^ 0x1BD11BDAu;
  x0 += k0; x1 += k1;
#define TFR(r) { x0 += x1; x1 = rotl32(x1, r); x1 ^= x0; }
  TFR(13) TFR(15) TFR(26) TFR(6)   x0 += k1; x1 += k2 + 1u;
  TFR(17) TFR(29) TFR(16) TFR(24)  x0 += k2; x1 += k0 + 2u;
  TFR(13) TFR(15) TFR(26) TFR(6)   x0 += k0; x1 += k1 + 3u;
  TFR(17) TFR(29) TFR(16) TFR(24)  x0 += k1; x1 += k2 + 4u;
  TFR(13) TFR(15) TFR(26) TFR(6)   x0 += k2; x1 += k0 + 5u;
#undef TFR
}

__device__ __forceinline__ float bits_to_u01(uint32_t bits) {
  return __fsub_rn(__uint_as_float((bits >> 9) | 0x3f800000u), 1.0f);
}

// XLA ErfInv32 (Giles), w = -log((1-x)(1+x)) exactly as ElementalIrEmitter
__device__ __forceinline__ float erfinv_f32(float x) {
  float w = -logf(__fmul_rn(__fsub_rn(1.0f, x), __fadd_rn(1.0f, x)));
  float p;
  if (w < 5.0f) {
    w = __fsub_rn(w, 2.5f);
    p = 2.81022636e-08f;
    p = __fadd_rn(__fmul_rn(p, w), 3.43273939e-07f);
    p = __fadd_rn(__fmul_rn(p, w), -3.5233877e-06f);
    p = __fadd_rn(__fmul_rn(p, w), -4.39150654e-06f);
    p = __fadd_rn(__fmul_rn(p, w), 0.00021858087f);
    p = __fadd_rn(__fmul_rn(p, w), -0.00125372503f);
    p = __fadd_rn(__fmul_rn(p, w), -0.00417768164f);
    p = __fadd_rn(__fmul_rn(p, w), 0.246640727f);
    p = __fadd_rn(__fmul_rn(p, w), 1.50140941f);
  } else {
    w = __fsub_rn(sqrtf(w), 3.0f);
    p = -0.000200214257f;
    p = __fadd_rn(__fmul_rn(p, w), 0.000100950558f);
    p = __fadd_rn(__fmul_rn(p, w), 0.00134934322f);
    p = __fadd_rn(__fmul_rn(p, w), -0.00367342844f);
    p = __fadd_rn(__fmul_rn(p, w), 0.00573950773f);
    p = __fadd_rn(__fmul_rn(p, w), -0.0076224613f);
    p = __fadd_rn(__fmul_rn(p, w), 0.00943887047f);
    p = __fadd_rn(__fmul_rn(p, w), 1.00167406f);
    p = __fadd_rn(__fmul_rn(p, w), 2.83297682f);
  }
  return __fmul_rn(p, x);
}

// fast sigmoid: 1/(1+exp(-x)) via native exp + native rcp (~1-2 ulp)
__device__ __forceinline__ float fast_sigmoid(float x) {
  float e = __expf(-x);
  return __builtin_amdgcn_rcpf(__fadd_rn(1.0f, e));
}

// ---------------- Kernel A: softmax-mixture mean/std + L(f32) ---------------
__global__ void prep_kernel(const float* __restrict__ mu,
                            const float* __restrict__ sig,
                            const float* __restrict__ pi,
                            float* __restrict__ sm, float* __restrict__ ss,
                            float* __restrict__ Lf) {
  int m = blockIdx.x * blockDim.x + threadIdx.x;
  if (m >= BB * NN) return;
  const float* pp = pi + m * KK;
  float mx = pp[0];
  for (int k = 1; k < KK; k++) mx = fmaxf(mx, pp[k]);
  float e[KK]; float s = 0.0f;
  for (int k = 0; k < KK; k++) { e[k] = expf(__fsub_rn(pp[k], mx)); s = __fadd_rn(s, e[k]); }
  float smv = 0.0f, ssv = 0.0f, eps = 0.0f;
  for (int k = 0; k < KK; k++) {
    float p = e[k] / s;
    smv = __fadd_rn(smv, __fmul_rn(p, mu[m * KK + k]));
    ssv = __fadd_rn(ssv, __fmul_rn(p, sig[m * KK + k]));
    eps = __fadd_rn(eps, pp[k]);
  }
  sm[m] = smv; ss[m] = ssv;
  float ep = fminf(fmaxf(eps, 1e-8f), 1.0f);
  float lep = logf(ep);
  float l1 = logf(__fsub_rn(1.0f, ep));
  Lf[m] = (float)((double)lep - (double)l1);
}

// -------- Kernel B: JAX partitionable-threefry RNG -> pm table + uniforms ----
__global__ void rng_kernel(const float* __restrict__ sm,
                           const float* __restrict__ ss,
                           float* __restrict__ pm, float* __restrict__ uacc) {
  int id = blockIdx.x * blockDim.x + threadIdx.x;
  if (id >= T_STEPS * BB * NN) return;
  int t = id >> 11;        // /2048
  int m = id & 2047;       // b*512+n

  uint32_t kk0 = 0u, kk1 = (uint32_t)t;
  tf2x32(0u, 42u, kk0, kk1);
  uint32_t n0 = 0u, n1 = 0u; tf2x32(kk0, kk1, n0, n1);   // k_noise
  uint32_t y0 = 0u, y1 = (uint32_t)m;
  tf2x32(n0, n1, y0, y1);
  uint32_t bits = y0 ^ y1;

  float u01 = bits_to_u01(bits);
  const float lo = -0.99999994f;  // nextafter(-1,0) f32; span rounds to 2.0f
  float u = fmaxf(lo, __fadd_rn(__fmul_rn(u01, 2.0f), lo));
  float z = __fmul_rn(1.41421356237309515f, erfinv_f32(u));
  pm[id] = __fadd_rn(sm[m], __fmul_rn(z, ss[m]));

  if (m < 4) {
    uint32_t u0 = 0u, u1 = 1u; tf2x32(kk0, kk1, u0, u1); // k_unif
    uint32_t c0 = 0u, c1 = (uint32_t)m;
    tf2x32(u0, u1, c0, c1);
    uacc[t * 4 + m] = bits_to_u01(c0 ^ c1);
  }
}

// ------- Kernel C: partial llt[t][b][j] = sum_{i in chunk} sgm(pm_i pm_j)*L[b,i]
template <int SPLIT>
__global__ __launch_bounds__(512) void ll_kernel(const float* __restrict__ pm,
                                                 const float* __restrict__ Lf,
                                                 const float* __restrict__ A0,
                                                 double* __restrict__ llt_p,
                                                 double* __restrict__ ll0_p) {
  constexpr int CH = NN / SPLIT;
  __shared__ float spm[CH];
  __shared__ float sLc[CH];
  int j = threadIdx.x;
  int bi = blockIdx.x;
  if (bi < TBTOT * SPLIT) {
    int tb = bi / SPLIT;
    int s = bi - tb * SPLIT;
    int b = tb & 3;
    int i0 = s * CH;
    if (j < CH) {
      spm[j] = pm[tb * NN + i0 + j];
      sLc[j] = Lf[b * NN + i0 + j];
    }
    float pmj = pm[tb * NN + j];
    __syncthreads();
    double acc = 0.0;
    #pragma unroll 8
    for (int i = 0; i < CH; i += 2) {
      float x0 = __fmul_rn(spm[i], pmj);
      float x1 = __fmul_rn(spm[i + 1], pmj);
      float t0 = __fmul_rn(fast_sigmoid(x0), sLc[i]);
      float t1 = __fmul_rn(fast_sigmoid(x1), sLc[i + 1]);
      acc += (double)__fadd_rn(t0, t1);
    }
    llt_p[(size_t)s * LLT_ELT + (size_t)tb * NN + j] = acc;
  } else {
    int bi2 = bi - TBTOT * SPLIT;
    int b = bi2 / SPLIT;
    int s = bi2 - b * SPLIT;
    int i0 = s * CH;
    if (j < CH) sLc[j] = Lf[b * NN + i0 + j];
    __syncthreads();
    double acc = 0.0;
    #pragma unroll 4
    for (int i = 0; i < CH; i++) {
      acc += (double)A0[(size_t)(i0 + i) * NN + j] * (double)sLc[i];
    }
    ll0_p[s * (BB * NN) + b * NN + j] = acc;
  }
}

// ------- Kernel C2: deterministic combine of partials ------------------------
template <int SPLIT>
__global__ __launch_bounds__(512) void combine_kernel(const double* __restrict__ llt_p,
                                                      const double* __restrict__ ll0_p,
                                                      double* __restrict__ llt,
                                                      double* __restrict__ ll0) {
  int bi = blockIdx.x;
  int j = threadIdx.x;
  if (bi < TBTOT) {
    size_t idx = (size_t)bi * NN + j;
    double a = llt_p[idx];
    #pragma unroll
    for (int s = 1; s < SPLIT; s++) a += llt_p[(size_t)s * LLT_ELT + idx];
    llt[idx] = a;
  } else {
    int idx = (bi - TBTOT) * NN + j;
    double a = ll0_p[idx];
    #pragma unroll
    for (int s = 1; s < SPLIT; s++) a += ll0_p[s * (BB * NN) + idx];
    ll0[idx] = a;
  }
}

// ------- Kernel D: sequential MCMC chain, 256 threads, prefetch depth 4 -----
// lane g owns j = 2g, 2g+1; 4 named register buffers (static idx only).
// KEY: in-loop barrier is a RAW s_barrier with lgkmcnt-only wait (LDS visible)
// so global prefetch loads stay IN FLIGHT across barriers (the compiler's
// __syncthreads would emit s_waitcnt vmcnt(0) and drain the pipeline).
#define CH_BARRIER() asm volatile("s_waitcnt lgkmcnt(0)\n\ts_barrier" ::: "memory")

#define CH_LOAD(BUF, T)                                                      \
  {                                                                          \
    _Pragma("unroll")                                                        \
    for (int b = 0; b < 4; b++)                                              \
      BUF[b] = llt2[((size_t)(T) * 4 + b) * 256 + g];                        \
  }

#define CH_STEP(BUF, T)                                                      \
  {                                                                          \
    float4 ua = sua[T];                                                      \
    double d0 = (BUF[0].x - cur[0].x) + (BUF[1].x - cur[1].x) +              \
                (BUF[2].x - cur[2].x) + (BUF[3].x - cur[3].x);               \
    double d1 = (BUF[0].y - cur[0].y) + (BUF[1].y - cur[1].y) +              \
                (BUF[2].y - cur[2].y) + (BUF[3].y - cur[3].y);               \
    float ps = __fadd_rn(fminf(__expf((float)d0), 1.0f),                     \
                         fminf(__expf((float)d1), 1.0f));                    \
    _Pragma("unroll")                                                        \
    for (int off = 32; off > 0; off >>= 1) ps += __shfl_xor(ps, off, 64);    \
    if ((g & 63) == 0) red[(T) & 1][g >> 6] = ps;                            \
    CH_BARRIER();                                                            \
    float ratio = (red[(T) & 1][0] + red[(T) & 1][1] + red[(T) & 1][2] +     \
                   red[(T) & 1][3]) * (1.0f / 512.0f);                       \
    if (ua.x < ratio) { st.x = (T); cur[0] = BUF[0]; }                       \
    if (ua.y < ratio) { st.y = (T); cur[1] = BUF[1]; }                       \
    if (ua.z < ratio) { st.z = (T); cur[2] = BUF[2]; }                       \
    if (ua.w < ratio) { st.w = (T); cur[3] = BUF[3]; }                       \
    if (g == 0) sst[T] = st;                                                 \
  }

__global__ __launch_bounds__(256, 1) void chain_kernel(const double* __restrict__ llt,
                                                       const double* __restrict__ ll0,
                                                       const float* __restrict__ uacc,
                                                       int* __restrict__ counts) {
  __shared__ float4 sua[T_STEPS];
  __shared__ int4 sst[T_STEPS];
  __shared__ int scnt[BB * (T_STEPS + 1)];
  __shared__ float red[2][4];
  int g = threadIdx.x;

  for (int t = g; t < T_STEPS; t += 256) {
    sua[t] = make_float4(uacc[4 * t], uacc[4 * t + 1],
                         uacc[4 * t + 2], uacc[4 * t + 3]);
  }

  const double2* llt2 = (const double2*)llt;
  const double2* ll02 = (const double2*)ll0;
  double2 cur[4];
  #pragma unroll
  for (int b = 0; b < 4; b++) cur[b] = ll02[b * 256 + g];
  int4 st = make_int4(-1, -1, -1, -1);

  double2 R0[4], R1[4], R2[4], R3[4];
  CH_LOAD(R0, 0)
  CH_LOAD(R1, 1)
  CH_LOAD(R2, 2)
  CH_LOAD(R3, 3)
  __syncthreads();  // sua ready (once; full barrier OK here)

  for (int t = 0; t < T_STEPS; t += 4) {
    CH_STEP(R0, t)
    if (t + 4 < T_STEPS) CH_LOAD(R0, t + 4)
    CH_STEP(R1, t + 1)
    if (t + 5 < T_STEPS) CH_LOAD(R1, t + 5)
    CH_STEP(R2, t + 2)
    if (t + 6 < T_STEPS) CH_LOAD(R2, t + 6)
    CH_STEP(R3, t + 3)
    if (t + 7 < T_STEPS) CH_LOAD(R3, t + 7)
  }

  __syncthreads();
  for (int s = g; s < BB * (T_STEPS + 1); s += 256) scnt[s] = 0;
  __syncthreads();
  for (int t = g; t < T_STEPS; t += 256) {
    int4 s4 = sst[t];
    atomicAdd(&scnt[0 * (T_STEPS + 1) + s4.x + 1], 1);
    atomicAdd(&scnt[1 * (T_STEPS + 1) + s4.y + 1], 1);
    atomicAdd(&scnt[2 * (T_STEPS + 1) + s4.z + 1], 1);
    atomicAdd(&scnt[3 * (T_STEPS + 1) + s4.w + 1], 1);
  }
  __syncthreads();
  for (int s = g; s < BB * (T_STEPS + 1); s += 256) counts[s] = scnt[s];
}

// ---------------- Kernel E: acc = sum_states count * A_state / num_samples --
__global__ __launch_bounds__(512) void out_kernel(const float* __restrict__ pm,
                                                  const float* __restrict__ A0,
                                                  const int* __restrict__ counts,
                                                  float* __restrict__ out) {
  __shared__ int scnt[T_STEPS + 1];
  int b = blockIdx.x >> 9;
  int i = blockIdx.x & 511;
  int j = threadIdx.x;
  if (j < T_STEPS + 1) scnt[j] = counts[b * (T_STEPS + 1) + j];
  __syncthreads();
  float r = (float)scnt[0] * A0[(size_t)i * NN + j];
  #pragma unroll 4
  for (int t = 0; t < T_STEPS; t++) {
    int c = scnt[t + 1];
    if (c) {
      float x = __fmul_rn(pm[(size_t)(t * BB + b) * NN + i],
                          pm[(size_t)(t * BB + b) * NN + j]);
      r += (float)c * fast_sigmoid(x);
    }
  }
  out[((size_t)b * NN + i) * NN + j] = r * 0.01f;
}

extern "C" void kernel_launch(void* const* d_in, const int* in_sizes, int n_in,
                              void* d_out, int out_size, void* d_ws, size_t ws_size,
                              hipStream_t stream) {
  const float* mu  = (const float*)d_in[0];
  const float* sig = (const float*)d_in[1];
  const float* pi  = (const float*)d_in[2];
  const float* A0  = (const float*)d_in[3];

  char* ws = (char*)d_ws;
  size_t off = 0;
  auto alloc = [&](size_t bytes) -> char* {
    char* p = ws + off;
    off += (bytes + 255) & ~(size_t)255;
    return p;
  };
  double* llt  = (double*)alloc(LLT_ELT * 8);        // 1,638,400
  double* ll0  = (double*)alloc(BB * NN * 8);        // 16,384
  float*  pm   = (float*)alloc(LLT_ELT * 4);         // 819,200
  float*  Lf   = (float*)alloc(BB * NN * 4);
  float*  sm   = (float*)alloc(BB * NN * 4);
  float*  ssv  = (float*)alloc(BB * NN * 4);
  float*  uacc = (float*)alloc(T_STEPS * 4 * 4);
  int*    cnts = (int*)alloc(BB * (T_STEPS + 1) * 4);
  size_t fixed_end = off;
  float*  outp = (float*)d_out;

  // choose SPLIT by available scratch for partial buffers
  size_t part4 = 4 * LLT_ELT * 8 + 4 * BB * NN * 8 + 1024;
  size_t part2 = 2 * LLT_ELT * 8 + 2 * BB * NN * 8 + 1024;
  int split = (ws_size >= fixed_end + part4) ? 4
            : (ws_size >= fixed_end + part2) ? 2 : 1;

  double* llt_p;
  double* ll0_p;
  if (split > 1) {
    llt_p = (double*)alloc((size_t)split * LLT_ELT * 8);
    ll0_p = (double*)alloc((size_t)split * BB * NN * 8);
  } else {
    llt_p = llt;  // write directly, no combine
    ll0_p = ll0;
  }

  prep_kernel<<<8, 256, 0, stream>>>(mu, sig, pi, sm, ssv, Lf);
  rng_kernel<<<(T_STEPS * BB * NN + 255) / 256, 256, 0, stream>>>(sm, ssv, pm, uacc);
  if (split == 4) {
    ll_kernel<4><<<(TBTOT + BB) * 4, 512, 0, stream>>>(pm, Lf, A0, llt_p, ll0_p);
    combine_kernel<4><<<TBTOT + BB, 512, 0, stream>>>(llt_p, ll0_p, llt, ll0);
  } else if (split == 2) {
    ll_kernel<2><<<(TBTOT + BB) * 2, 512, 0, stream>>>(pm, Lf, A0, llt_p, ll0_p);
    combine_kernel<2><<<TBTOT + BB, 512, 0, stream>>>(llt_p, ll0_p, llt, ll0);
  } else {
    ll_kernel<1><<<TBTOT + BB, 512, 0, stream>>>(pm, Lf, A0, llt_p, ll0_p);
  }
  chain_kernel<<<1, 256, 0, stream>>>(llt, ll0, uacc, cnts);
  out_kernel<<<BB * NN, 512, 0, stream>>>(pm, A0, cnts, outp);
}